// Round 2
// baseline (249.300 us; speedup 1.0000x reference)
//
#include <hip/hip_runtime.h>
#include <hip/hip_bf16.h>
#include <hip/hip_cooperative_groups.h>

namespace cg = cooperative_groups;

// Problem constants
#define NN    32
#define CC    49
#define HWSZ  81
#define MSZ   24
#define KSZ   7
#define PADSZ 3
#define NHW   (NN*HWSZ)     // 2592
#define NCHW  (NN*CC*HWSZ)  // 127008

// LDS strides (in shorts / bf16 elements). All row strides * 2B are multiples
// of 16B (b128-aligned fragment loads). Total LDS = 13312+13312+13824+9216
// = 49664 B (+32 B reduce scratch) -> exactly 3 blocks/CU -> grid 768 fully
// co-resident (required for cooperative grid.sync).
#define XSB_S  104   // xsb[64][104]  : x[n] as bf16 (pads zeroed surgically)
#define MSK_S  104   // msk[64][104]  : mask rows dd (fully zero-filled)
#define MSKT_S 72    // mskT[96][72]  : mask transposed (fully zero-filled)
#define G_S    72    // gm[64][72]    : leaky(fk)[c][dd] (fully overwritten)

typedef __attribute__((ext_vector_type(8))) short short8;
typedef __attribute__((ext_vector_type(4))) short short4v;
typedef __attribute__((ext_vector_type(4))) float f32x4;

__device__ __forceinline__ short f2b(float v) {
    unsigned u = __float_as_uint(v);
    u += 0x7fffu + ((u >> 16) & 1u);      // round-to-nearest-even to bf16
    return (short)(u >> 16);
}
__device__ __forceinline__ float b2f(short s) {
    return __uint_as_float(((unsigned)(unsigned short)s) << 16);
}

// Single cooperative kernel. Grid (MSZ, NN) = (24, 32) = 768 blocks x 256 thr.
// Each block owns (o = blockIdx.x, n = blockIdx.y) — round-0's fully parallel
// decomposition (no o-serialization: that cost +3.3 us in round 1).
//   phase A: stage x->xsb + surgical pad-zero + full msk/mskT zero; BARRIER
//   phase B: conv(K=7 over channel)+softmax(81) from xsb; 4 rows/wave.
//            Softmax WITHOUT max-subtraction: |logit| <= ~13 -> exp <= 5e5,
//            sum <= 4e7, safe in fp32. BARRIER
//   phase C: MFMA fkT[dd][c] = msk(64x96).xsb^T -> leaky -> gm[c][dd]; BARRIER
//   phase D: MFMA out_partial[c][hw] = gm(64x64).mskT^T -> fp32 atomicAdd
//            into out[n] (pre-zeroed by a hipMemsetAsync node). 3969 live
//            adds/block, 24-way contention/address, all L2-resident.
//   grid.sync(); then blocks flat<49 run batch-norm for channel c=flat
//            (two-pass over (N,H,W): no runtime-indexed register arrays).
// NaN-safety: every LDS word an MFMA reads is real data or explicit 0.
__global__ __launch_bounds__(256, 3) void fuse_all(
    const float* __restrict__ x, const float* __restrict__ cw,
    const float* __restrict__ cb, const float* __restrict__ gamma,
    const float* __restrict__ beta, float* __restrict__ out)
{
    __shared__ short xsb [64 * XSB_S];    // 13312 B
    __shared__ short msk [64 * MSK_S];    // 13312 B
    __shared__ short mskT[96 * MSKT_S];   // 13824 B
    __shared__ short gm  [64 * G_S];      //  9216 B
    __shared__ float rs[4], rq[4];        //    32 B (BN reduce)

    const int o = blockIdx.x;          // 0..23
    const int n = blockIdx.y;          // 0..31
    const int t = threadIdx.x;
    const int lane = t & 63;
    const int wv = t >> 6;             // 0..3
    const int lr = lane & 15;
    const int lq = lane >> 4;          // quad index 0..3

    const float* xg = x + (size_t)n * CC * HWSZ;
    float wk[KSZ];
    #pragma unroll
    for (int k = 0; k < KSZ; ++k) wk[k] = cw[o * KSZ + k];
    const float bias = cb[o];

    // ---- phase A: all writes disjoint ----
    const f32x4 z4 = {0.f, 0.f, 0.f, 0.f};
    // (a) stage x[n] data into xsb rows 0-48, cols 0-80
    for (int i = t; i < CC * HWSZ; i += 256) {
        int c = i / HWSZ, hw = i - c * HWSZ;
        xsb[c * XSB_S + hw] = f2b(xg[i]);
    }
    // (b) xsb pad cols 81..103 of rows 0-48 (scalar 81-87, b128 88-103)
    if (t < CC) {
        short* row = xsb + t * XSB_S;
        #pragma unroll
        for (int cq = 81; cq < 88; ++cq) row[cq] = 0;
        *(f32x4*)(row + 88) = z4;
        *(f32x4*)(row + 96) = z4;
    }
    // (c) xsb rows 49-63 full zero (15 rows x 13 b128-groups)
    for (int j = t; j < 15 * 13; j += 256) {
        int rr = j / 13, cg = j - rr * 13;
        *(f32x4*)(xsb + (49 + rr) * XSB_S + cg * 8) = z4;
    }
    // (d) msk / mskT full zero
    for (int i = t; i < 832; i += 256) ((f32x4*)msk)[i] = z4;
    for (int i = t; i < 864; i += 256) ((f32x4*)mskT)[i] = z4;
    __syncthreads();

    // ---- phase B: conv + softmax (no max-sub); 4 rows per wave (row = lq).
    // Lane lr covers cols [4lr,4lr+4) (b64), col 64+lr, and col 80 on lr==0.
    #pragma unroll
    for (int it = 0; it < 4; ++it) {
        int dd = it * 16 + wv * 4 + lq;
        if (dd < CC) {
            float a0 = 0.f, a1 = 0.f, a2 = 0.f, a3 = 0.f, a4 = 0.f, a5 = 0.f;
            #pragma unroll
            for (int k = 0; k < KSZ; ++k) {
                int r = dd + k - PADSZ;
                if (r >= 0 && r < CC) {
                    const short* xr = xsb + r * XSB_S;
                    short4v xa = *(const short4v*)(xr + 4 * lr);
                    float w = wk[k];
                    a0 += w * b2f(xa[0]);
                    a1 += w * b2f(xa[1]);
                    a2 += w * b2f(xa[2]);
                    a3 += w * b2f(xa[3]);
                    a4 += w * b2f(xr[64 + lr]);
                    if (lr == 0) a5 += w * b2f(xr[80]);
                }
            }
            float e0 = __expf(a0 + bias), e1 = __expf(a1 + bias);
            float e2 = __expf(a2 + bias), e3 = __expf(a3 + bias);
            float e4 = __expf(a4 + bias);
            float e5 = (lr == 0) ? __expf(a5 + bias) : 0.f;
            float s = ((e0 + e1) + (e2 + e3)) + (e4 + e5);
            #pragma unroll
            for (int off = 8; off; off >>= 1) s += __shfl_xor(s, off, 64);
            float inv = __builtin_amdgcn_rcpf(s);
            short4v pk;
            pk[0] = f2b(e0 * inv); pk[1] = f2b(e1 * inv);
            pk[2] = f2b(e2 * inv); pk[3] = f2b(e3 * inv);
            short b4 = f2b(e4 * inv);
            short* mrow = msk + dd * MSK_S;
            *(short4v*)(mrow + 4 * lr) = pk;        // b64, 8B-aligned
            mrow[64 + lr] = b4;
            mskT[(4 * lr    ) * MSKT_S + dd] = pk[0];
            mskT[(4 * lr + 1) * MSKT_S + dd] = pk[1];
            mskT[(4 * lr + 2) * MSKT_S + dd] = pk[2];
            mskT[(4 * lr + 3) * MSKT_S + dd] = pk[3];
            mskT[(64 + lr   ) * MSKT_S + dd] = b4;
            if (lr == 0) {
                short b5 = f2b(e5 * inv);
                mrow[80] = b5;
                mskT[80 * MSKT_S + dd] = b5;
            }
        }
    }
    __syncthreads();

    // ---- phase C (MFMA): fkT[dd][c] = sum_hw msk[dd][hw] * xsb[c][hw]
    // M=dd (4 tiles, one per wave), N=c (4 tiles), K=hw (96, 3 steps).
    {
        short8 a2[3];
        #pragma unroll
        for (int ks = 0; ks < 3; ++ks)
            a2[ks] = *(const short8*)&msk[(wv * 16 + lr) * MSK_S + ks * 32 + lq * 8];
        #pragma unroll
        for (int nt = 0; nt < 4; ++nt) {
            f32x4 accv = {0.f, 0.f, 0.f, 0.f};
            #pragma unroll
            for (int ks = 0; ks < 3; ++ks) {
                short8 b = *(const short8*)&xsb[(nt * 16 + lr) * XSB_S + ks * 32 + lq * 8];
                accv = __builtin_amdgcn_mfma_f32_16x16x32_bf16(a2[ks], b, accv, 0, 0, 0);
            }
            // C-layout: lane holds fkT[dd = wv*16 + lq*4 + r][c = nt*16 + lr]
            short4v pk;
            #pragma unroll
            for (int r = 0; r < 4; ++r) {
                float v = accv[r];
                v = (v >= 0.f) ? v : 0.01f * v;
                pk[r] = f2b(v);
            }
            *(short4v*)&gm[(nt * 16 + lr) * G_S + wv * 16 + lq * 4] = pk;
        }
    }
    __syncthreads();

    // ---- phase D (MFMA): out_partial[c][hw] = sum_dd gm[c][dd] * mskT[hw][dd]
    // M=c (4 tiles, one per wave), N=hw (6 tiles), K=dd (64, 2 steps).
    // Epilogue: fp32 atomicAdd into out[n] (pre-zeroed).
    {
        float* dstn = out + (size_t)n * CC * HWSZ;
        short8 a1[2];
        #pragma unroll
        for (int ks = 0; ks < 2; ++ks)
            a1[ks] = *(const short8*)&gm[(wv * 16 + lr) * G_S + ks * 32 + lq * 8];
        #pragma unroll
        for (int nt = 0; nt < 6; ++nt) {
            f32x4 accv = {0.f, 0.f, 0.f, 0.f};
            #pragma unroll
            for (int ks = 0; ks < 2; ++ks) {
                short8 b = *(const short8*)&mskT[(nt * 16 + lr) * MSKT_S + ks * 32 + lq * 8];
                accv = __builtin_amdgcn_mfma_f32_16x16x32_bf16(a1[ks], b, accv, 0, 0, 0);
            }
            int hw = nt * 16 + lr;
            if (hw < HWSZ) {
                int cb4 = wv * 16 + lq * 4;
                #pragma unroll
                for (int r = 0; r < 4; ++r) {
                    int c = cb4 + r;
                    if (c < CC) atomicAdd(dstn + c * HWSZ + hw, accv[r]);
                }
            }
        }
    }

    // ---- grid-wide barrier: all 768 blocks' atomics must land before BN ----
    __threadfence();                 // release: make atomics visible device-wide
    cg::this_grid().sync();
    __threadfence();                 // acquire: invalidate stale L1/L2 lines

    // ---- batch-norm epilogue: blocks flat<49 each handle one channel ----
    const int flat = blockIdx.y * MSZ + blockIdx.x;
    if (flat < CC) {
        const int c = flat;
        float sum = 0.f, sq = 0.f;
        for (int i = t; i < NHW; i += 256) {
            int nn2 = i / HWSZ;
            int hw = i - nn2 * HWSZ;
            int idx = (nn2 * CC + c) * HWSZ + hw;
            float v = out[idx] + x[idx];
            sum += v; sq += v * v;
        }
        #pragma unroll
        for (int off = 32; off; off >>= 1) {
            sum += __shfl_xor(sum, off, 64);
            sq  += __shfl_xor(sq, off, 64);
        }
        if (lane == 0) { rs[wv] = sum; rq[wv] = sq; }
        __syncthreads();
        float ts = rs[0] + rs[1] + rs[2] + rs[3];
        float tq = rq[0] + rq[1] + rq[2] + rq[3];
        const float invD = 1.f / (float)NHW;
        float mean = ts * invD;
        float var  = tq * invD - mean * mean;
        float scal = rsqrtf(var + 1e-5f) * gamma[c];
        float shft = beta[c] - mean * scal;
        // pass 2: recompute v (L2-hot) and write normalized result
        for (int i = t; i < NHW; i += 256) {
            int nn2 = i / HWSZ;
            int hw = i - nn2 * HWSZ;
            int idx = (nn2 * CC + c) * HWSZ + hw;
            float v = out[idx] + x[idx];
            out[idx] = v * scal + shft;
        }
    }
}

extern "C" void kernel_launch(void* const* d_in, const int* in_sizes, int n_in,
                              void* d_out, int out_size, void* d_ws, size_t ws_size,
                              hipStream_t stream) {
    const float* x     = (const float*)d_in[0];
    const float* cw    = (const float*)d_in[1];
    const float* cb    = (const float*)d_in[2];
    const float* gamma = (const float*)d_in[3];
    const float* beta  = (const float*)d_in[4];
    float* out = (float*)d_out;

    // Zero the accumulation target (harness re-poisons out each iteration).
    hipMemsetAsync(out, 0, (size_t)NCHW * sizeof(float), stream);

    void* args[] = {(void*)&x, (void*)&cw, (void*)&cb,
                    (void*)&gamma, (void*)&beta, (void*)&out};
    hipLaunchCooperativeKernel((const void*)fuse_all, dim3(MSZ, NN), dim3(256),
                               args, 0, stream);
}

// Round 3
// 80.953 us; speedup vs baseline: 3.0796x; 3.0796x over previous
//
#include <hip/hip_runtime.h>
#include <hip/hip_bf16.h>

// Problem constants
#define NN    32
#define CC    49
#define HWSZ  81
#define MSZ   24
#define KSZ   7
#define PADSZ 3
#define NHW   (NN*HWSZ)     // 2592
#define NCHW  (NN*CC*HWSZ)  // 127008

// LDS strides (in shorts / bf16 elements). All row strides * 2B are multiples
// of 16B (b128-aligned fragment loads). Total LDS = 13312 + 13312 + 13824 +
// 9216 = 49664 B < 52 KB -> 3 blocks/CU, grid 768 = 256 CU x 3 -> fully
// resident in one round.
#define XSB_S  104   // xsb[64][104]  : x[n] as bf16 (pads zeroed surgically)
#define MSK_S  104   // msk[64][104]  : mask rows dd (fully zero-filled)
#define MSKT_S 72    // mskT[96][72]  : mask transposed (fully zero-filled)
#define G_S    72    // gm[64][72]    : leaky(fk)[c][dd] (fully overwritten)

// k2 n-grouping: 8 groups of 4 n's -> grid (49, 8) = 392 blocks.
#define NGRP  8
#define NPG   (NN/NGRP)        // 4
#define EPB   (NPG*HWSZ)       // 324 elements per (c, group) block

typedef __attribute__((ext_vector_type(8))) short short8;
typedef __attribute__((ext_vector_type(4))) short short4v;
typedef __attribute__((ext_vector_type(4))) float f32x4;

__device__ __forceinline__ short f2b(float v) {
    unsigned u = __float_as_uint(v);
    u += 0x7fffu + ((u >> 16) & 1u);      // round-to-nearest-even to bf16
    return (short)(u >> 16);
}
__device__ __forceinline__ float b2f(short s) {
    return __uint_as_float(((unsigned)(unsigned short)s) << 16);
}

// Kernel 1 (UNCHANGED from the verified 79.96us round-0 kernel):
// one block (256 thr = 4 waves) per (n, o).
//   phase A: stage x->xsb + surgical pad-zero + full msk/mskT zero; BARRIER
//   phase B: conv(K=7 over channel)+softmax(81) from xsb, 4 rows/wave.
//            Softmax WITHOUT max-subtraction: |logit| <= ~13 -> exp <= 5e5,
//            sum <= 4e7, safe in fp32. BARRIER
//   phase C: MFMA fkT[dd][c] = msk(64x96).xsb^T -> leaky -> gm[c][dd]; BARRIER
//   phase D: MFMA out_partial[c][hw] = gm(64x64).mskT^T
//            use_ws=1: coalesced BF16 stores to bws[o][n][c][hw]
//            use_ws=0: fp32 atomicAdd into acc[n][c][hw] (fallback)
// NaN-safety: every LDS word an MFMA reads is real data or explicit 0.
__global__ __launch_bounds__(256) void fuse_k1(
    const float* __restrict__ x, const float* __restrict__ cw,
    const float* __restrict__ cb, float* __restrict__ acc, int use_ws)
{
    __shared__ short xsb [64 * XSB_S];    // 13312 B
    __shared__ short msk [64 * MSK_S];    // 13312 B
    __shared__ short mskT[96 * MSKT_S];   // 13824 B
    __shared__ short gm  [64 * G_S];      //  9216 B

    const int o = blockIdx.x;          // 0..23
    const int n = blockIdx.y;          // 0..31
    const int t = threadIdx.x;
    const int lane = t & 63;
    const int wv = t >> 6;             // 0..3
    const int lr = lane & 15;
    const int lq = lane >> 4;          // quad index 0..3

    const float* xg = x + (size_t)n * CC * HWSZ;
    float wk[KSZ];
    #pragma unroll
    for (int k = 0; k < KSZ; ++k) wk[k] = cw[o * KSZ + k];
    const float bias = cb[o];

    // ---- phase A: all writes disjoint ----
    const f32x4 z4 = {0.f, 0.f, 0.f, 0.f};
    // (a) stage x[n] data into xsb rows 0-48, cols 0-80
    for (int i = t; i < CC * HWSZ; i += 256) {
        int c = i / HWSZ, hw = i - c * HWSZ;
        xsb[c * XSB_S + hw] = f2b(xg[i]);
    }
    // (b) xsb pad cols 81..103 of rows 0-48 (scalar 81-87, b128 88-103)
    if (t < CC) {
        short* row = xsb + t * XSB_S;
        #pragma unroll
        for (int cq = 81; cq < 88; ++cq) row[cq] = 0;
        *(f32x4*)(row + 88) = z4;
        *(f32x4*)(row + 96) = z4;
    }
    // (c) xsb rows 49-63 full zero (15 rows x 13 b128-groups)
    for (int j = t; j < 15 * 13; j += 256) {
        int rr = j / 13, cg = j - rr * 13;
        *(f32x4*)(xsb + (49 + rr) * XSB_S + cg * 8) = z4;
    }
    // (d) msk / mskT full zero
    for (int i = t; i < 832; i += 256) ((f32x4*)msk)[i] = z4;
    for (int i = t; i < 864; i += 256) ((f32x4*)mskT)[i] = z4;
    __syncthreads();

    // ---- phase B: conv + softmax (no max-sub); 4 rows per wave (row = lq).
    // Lane lr covers cols [4lr,4lr+4) (b64), col 64+lr, and col 80 on lr==0.
    #pragma unroll
    for (int it = 0; it < 4; ++it) {
        int dd = it * 16 + wv * 4 + lq;
        if (dd < CC) {
            float a0 = 0.f, a1 = 0.f, a2 = 0.f, a3 = 0.f, a4 = 0.f, a5 = 0.f;
            #pragma unroll
            for (int k = 0; k < KSZ; ++k) {
                int r = dd + k - PADSZ;
                if (r >= 0 && r < CC) {
                    const short* xr = xsb + r * XSB_S;
                    short4v xa = *(const short4v*)(xr + 4 * lr);
                    float w = wk[k];
                    a0 += w * b2f(xa[0]);
                    a1 += w * b2f(xa[1]);
                    a2 += w * b2f(xa[2]);
                    a3 += w * b2f(xa[3]);
                    a4 += w * b2f(xr[64 + lr]);
                    if (lr == 0) a5 += w * b2f(xr[80]);
                }
            }
            float e0 = __expf(a0 + bias), e1 = __expf(a1 + bias);
            float e2 = __expf(a2 + bias), e3 = __expf(a3 + bias);
            float e4 = __expf(a4 + bias);
            float e5 = (lr == 0) ? __expf(a5 + bias) : 0.f;
            float s = ((e0 + e1) + (e2 + e3)) + (e4 + e5);
            #pragma unroll
            for (int off = 8; off; off >>= 1) s += __shfl_xor(s, off, 64);
            float inv = __builtin_amdgcn_rcpf(s);
            short4v pk;
            pk[0] = f2b(e0 * inv); pk[1] = f2b(e1 * inv);
            pk[2] = f2b(e2 * inv); pk[3] = f2b(e3 * inv);
            short b4 = f2b(e4 * inv);
            short* mrow = msk + dd * MSK_S;
            *(short4v*)(mrow + 4 * lr) = pk;        // b64, 8B-aligned
            mrow[64 + lr] = b4;
            mskT[(4 * lr    ) * MSKT_S + dd] = pk[0];
            mskT[(4 * lr + 1) * MSKT_S + dd] = pk[1];
            mskT[(4 * lr + 2) * MSKT_S + dd] = pk[2];
            mskT[(4 * lr + 3) * MSKT_S + dd] = pk[3];
            mskT[(64 + lr   ) * MSKT_S + dd] = b4;
            if (lr == 0) {
                short b5 = f2b(e5 * inv);
                mrow[80] = b5;
                mskT[80 * MSKT_S + dd] = b5;
            }
        }
    }
    __syncthreads();

    // ---- phase C (MFMA): fkT[dd][c] = sum_hw msk[dd][hw] * xsb[c][hw]
    // M=dd (4 tiles, one per wave), N=c (4 tiles), K=hw (96, 3 steps).
    {
        short8 a2[3];
        #pragma unroll
        for (int ks = 0; ks < 3; ++ks)
            a2[ks] = *(const short8*)&msk[(wv * 16 + lr) * MSK_S + ks * 32 + lq * 8];
        #pragma unroll
        for (int nt = 0; nt < 4; ++nt) {
            f32x4 accv = {0.f, 0.f, 0.f, 0.f};
            #pragma unroll
            for (int ks = 0; ks < 3; ++ks) {
                short8 b = *(const short8*)&xsb[(nt * 16 + lr) * XSB_S + ks * 32 + lq * 8];
                accv = __builtin_amdgcn_mfma_f32_16x16x32_bf16(a2[ks], b, accv, 0, 0, 0);
            }
            // C-layout: lane holds fkT[dd = wv*16 + lq*4 + r][c = nt*16 + lr]
            short4v pk;
            #pragma unroll
            for (int r = 0; r < 4; ++r) {
                float v = accv[r];
                v = (v >= 0.f) ? v : 0.01f * v;
                pk[r] = f2b(v);
            }
            *(short4v*)&gm[(nt * 16 + lr) * G_S + wv * 16 + lq * 4] = pk;
        }
    }
    __syncthreads();

    // ---- phase D (MFMA): out_partial[c][hw] = sum_dd gm[c][dd] * mskT[hw][dd]
    // M=c (4 tiles, one per wave), N=hw (6 tiles), K=dd (64, 2 steps).
    {
        short* bws = (short*)acc + (size_t)(o * NN + n) * CC * HWSZ;  // bf16 ws
        float* dstn = acc + (size_t)n * CC * HWSZ;                    // fallback
        short8 a1[2];
        #pragma unroll
        for (int ks = 0; ks < 2; ++ks)
            a1[ks] = *(const short8*)&gm[(wv * 16 + lr) * G_S + ks * 32 + lq * 8];
        #pragma unroll
        for (int nt = 0; nt < 6; ++nt) {
            f32x4 accv = {0.f, 0.f, 0.f, 0.f};
            #pragma unroll
            for (int ks = 0; ks < 2; ++ks) {
                short8 b = *(const short8*)&mskT[(nt * 16 + lr) * MSKT_S + ks * 32 + lq * 8];
                accv = __builtin_amdgcn_mfma_f32_16x16x32_bf16(a1[ks], b, accv, 0, 0, 0);
            }
            int hw = nt * 16 + lr;
            if (hw < HWSZ) {
                int cb = wv * 16 + lq * 4;
                if (use_ws) {
                    #pragma unroll
                    for (int r = 0; r < 4; ++r) {
                        int c = cb + r;
                        if (c < CC) bws[c * HWSZ + hw] = f2b(accv[r]);
                    }
                } else {
                    #pragma unroll
                    for (int r = 0; r < 4; ++r) {
                        int c = cb + r;
                        if (c < CC) atomicAdd(dstn + c * HWSZ + hw, accv[r]);
                    }
                }
            }
        }
    }
}

// Kernel 2a (ws path): grid (49, 8) = 392 blocks x 256 thr. Block (c, g)
// handles n in [4g, 4g+4) -> 324 elements. Gathers the 24 per-o bf16
// partials (4 independent fp32 accumulators for MLP) + fp32 residual,
// writes v to out (fp32, disjoint), and one float2{sum, sq} partial to
// psum[c*8+g]. 8x the block parallelism of the old 49-block k2w: the
// 254KB-strided 24-way gather latency is now hidden by ~1.5 blocks/CU
// device-wide instead of 49 busy CUs.
__global__ __launch_bounds__(256) void fuse_k2a(
    const short* __restrict__ bws, const float* __restrict__ x,
    float* __restrict__ out, float2* __restrict__ psum)
{
    const int c = blockIdx.x;          // 0..48
    const int g = blockIdx.y;          // 0..7
    const int t = threadIdx.x;
    float sum = 0.f, sq = 0.f;
    for (int i = t; i < EPB; i += 256) {
        int nl = i / HWSZ;
        int hw = i - nl * HWSZ;
        int idx = (((g * NPG + nl) * CC) + c) * HWSZ + hw;
        const short* p = bws + idx;
        float v0 = x[idx], v1 = 0.f, v2 = 0.f, v3 = 0.f;
        #pragma unroll
        for (int o = 0; o < MSZ; o += 4) {
            v0 += b2f(p[(size_t)(o    ) * NCHW]);
            v1 += b2f(p[(size_t)(o + 1) * NCHW]);
            v2 += b2f(p[(size_t)(o + 2) * NCHW]);
            v3 += b2f(p[(size_t)(o + 3) * NCHW]);
        }
        float v = (v0 + v1) + (v2 + v3);
        out[idx] = v;
        sum += v; sq += v * v;
    }
    #pragma unroll
    for (int off = 32; off; off >>= 1) {
        sum += __shfl_xor(sum, off, 64);
        sq  += __shfl_xor(sq, off, 64);
    }
    __shared__ float rs[4], rq[4];
    const int lane = t & 63, wv = t >> 6;
    if (lane == 0) { rs[wv] = sum; rq[wv] = sq; }
    __syncthreads();
    if (t == 0) {
        float2 pv;
        pv.x = (rs[0] + rs[1]) + (rs[2] + rs[3]);
        pv.y = (rq[0] + rq[1]) + (rq[2] + rq[3]);
        psum[c * NGRP + g] = pv;
    }
}

// Kernel 2b (ws path): grid (49, 8). Reads the 8 partials for its channel
// (64 B, L2-broadcast), computes scale/shift, normalizes out in place
// (L2-hot 1 MB read + write).
__global__ __launch_bounds__(256) void fuse_k2b(
    const float2* __restrict__ psum, const float* __restrict__ gamma,
    const float* __restrict__ beta, float* __restrict__ out)
{
    const int c = blockIdx.x;
    const int g = blockIdx.y;
    const int t = threadIdx.x;
    float ts = 0.f, tq = 0.f;
    #pragma unroll
    for (int w = 0; w < NGRP; ++w) {
        float2 pv = psum[c * NGRP + w];
        ts += pv.x; tq += pv.y;
    }
    const float invD = 1.f / (float)NHW;
    float mean = ts * invD;
    float var  = tq * invD - mean * mean;
    float scal = rsqrtf(var + 1e-5f) * gamma[c];
    float shft = beta[c] - mean * scal;
    for (int i = t; i < EPB; i += 256) {
        int nl = i / HWSZ;
        int hw = i - nl * HWSZ;
        int idx = (((g * NPG + nl) * CC) + c) * HWSZ + hw;
        out[idx] = out[idx] * scal + shft;
    }
}

// Kernel 2 (fallback, atomic path): residual add + batch-norm in-place on d_out.
__global__ __launch_bounds__(1024) void fuse_k2(
    float* __restrict__ out, const float* __restrict__ x,
    const float* __restrict__ gamma, const float* __restrict__ beta)
{
    const int c = blockIdx.x;
    const int t = threadIdx.x;
    float vals[3];
    float sum = 0.f, sq = 0.f;
    int cnt = 0;
    for (int i = t; i < NHW; i += 1024) {
        int n = i / HWSZ;
        int hw = i - n * HWSZ;
        int idx = (n * CC + c) * HWSZ + hw;
        float v = out[idx] + x[idx];
        vals[cnt++] = v;
        sum += v; sq += v * v;
    }
    #pragma unroll
    for (int off = 32; off; off >>= 1) {
        sum += __shfl_xor(sum, off, 64);
        sq  += __shfl_xor(sq, off, 64);
    }
    __shared__ float rs[16], rq[16];
    const int lane = t & 63, wv = t >> 6;
    if (lane == 0) { rs[wv] = sum; rq[wv] = sq; }
    __syncthreads();
    float ts = 0.f, tq = 0.f;
    #pragma unroll
    for (int w = 0; w < 16; ++w) { ts += rs[w]; tq += rq[w]; }
    const float invD = 1.f / (float)NHW;
    float mean = ts * invD;
    float var  = tq * invD - mean * mean;
    float scal = rsqrtf(var + 1e-5f) * gamma[c];
    float shft = beta[c] - mean * scal;
    cnt = 0;
    for (int i = t; i < NHW; i += 1024) {
        int n = i / HWSZ;
        int hw = i - n * HWSZ;
        out[(n * CC + c) * HWSZ + hw] = vals[cnt++] * scal + shft;
    }
}

extern "C" void kernel_launch(void* const* d_in, const int* in_sizes, int n_in,
                              void* d_out, int out_size, void* d_ws, size_t ws_size,
                              hipStream_t stream) {
    const float* x     = (const float*)d_in[0];
    const float* cw    = (const float*)d_in[1];
    const float* cb    = (const float*)d_in[2];
    const float* gamma = (const float*)d_in[3];
    const float* beta  = (const float*)d_in[4];
    float* out = (float*)d_out;

    const size_t bws_bytes  = (size_t)MSZ * NCHW * sizeof(short);   // 6.1 MB
    const size_t psum_off   = bws_bytes;                            // 8B-aligned
    const size_t need = psum_off + (size_t)CC * NGRP * sizeof(float2);
    if (ws_size >= need) {
        float2* psum = (float2*)((char*)d_ws + psum_off);
        fuse_k1<<<dim3(MSZ, NN), 256, 0, stream>>>(x, cw, cb, (float*)d_ws, 1);
        fuse_k2a<<<dim3(CC, NGRP), 256, 0, stream>>>((const short*)d_ws, x, out, psum);
        fuse_k2b<<<dim3(CC, NGRP), 256, 0, stream>>>(psum, gamma, beta, out);
    } else {
        hipMemsetAsync(out, 0, (size_t)NCHW * sizeof(float), stream);
        fuse_k1<<<dim3(MSZ, NN), 256, 0, stream>>>(x, cw, cb, out, 0);
        fuse_k2<<<CC, 1024, 0, stream>>>(out, x, gamma, beta);
    }
}

// Round 5
// 80.124 us; speedup vs baseline: 3.1114x; 1.0103x over previous
//
#include <hip/hip_runtime.h>
#include <hip/hip_bf16.h>

// Problem constants
#define NN    32
#define CC    49
#define HWSZ  81
#define MSZ   24
#define KSZ   7
#define PADSZ 3
#define NHW   (NN*HWSZ)     // 2592
#define NCHW  (NN*CC*HWSZ)  // 127008

// LDS strides (in shorts / bf16 elements). All row strides * 2B are multiples
// of 16B (b128-aligned fragment loads). Total LDS = 13312 + 13312 + 13824 +
// 9216 = 49664 B < 52 KB -> 3 blocks/CU, grid 768 = 256 CU x 3 -> fully
// resident in one round.
#define XSB_S  104   // xsb[64][104]  : x[n] as bf16 (pads zeroed surgically)
#define MSK_S  104   // msk[64][104]  : mask rows dd (pads zeroed surgically)
#define MSKT_S 72    // mskT[96][72]  : mask transposed (pads zeroed surgically)
#define G_S    72    // gm[64][72]    : leaky(fk)[c][dd] (fully overwritten)

typedef __attribute__((ext_vector_type(8))) short short8;
typedef __attribute__((ext_vector_type(4))) short short4v;
typedef __attribute__((ext_vector_type(4))) float f32x4;

__device__ __forceinline__ short f2b(float v) {
    unsigned u = __float_as_uint(v);
    u += 0x7fffu + ((u >> 16) & 1u);      // round-to-nearest-even to bf16
    return (short)(u >> 16);
}
__device__ __forceinline__ float b2f(short s) {
    return __uint_as_float(((unsigned)(unsigned short)s) << 16);
}

// Kernel 1: one block (256 thr = 4 waves) per (n, o). Structure identical to
// the verified 79.96us round-0 kernel; phase-A zeroing trimmed to exactly the
// LDS words MFMA reads (saves ~1100 b128 stores/block, zero correctness risk:
// every trimmed word is provably never read).
//   phase A: stage x->xsb + surgical pad-zero of xsb/msk/mskT; BARRIER
//   phase B: conv(K=7 over channel)+softmax(81) from xsb, 4 rows/wave.
//            Softmax WITHOUT max-subtraction: |logit| <= ~13 -> exp <= 5e5,
//            sum <= 4e7, safe in fp32. BARRIER
//   phase C: MFMA fkT[dd][c] = msk(64x96).xsb^T -> leaky -> gm[c][dd]; BARRIER
//   phase D: MFMA out_partial[c][hw] = gm(64x64).mskT^T
//            use_ws=1: coalesced BF16 stores to bws[o][n][c][hw]
//            use_ws=0: fp32 atomicAdd into acc[n][c][hw] (fallback)
// Read-coverage audit (what must be zero):
//   xsb : B reads cols<=80 (real); C-B-frag reads rows 0-63, cols 0-95.
//         -> rows 49-63 cols 0-103 zeroed (loop c), rows 0-48 cols 81-103 (b).
//   msk : C-A-frag reads rows 0-63, cols 0-95. B writes rows 0-48 cols 0-80
//         (after barrier -> zeroing col 80 in A is safe, no race).
//         -> zero rows 49-63 cols 0-95 + rows 0-48 cols 80-95.
//   mskT: D-B-frag reads rows 0-95, cols 0-63. B writes rows 0-80 cols 0-48.
//         -> zero rows 0-80 cols 48-63 + rows 81-95 cols 0-63.
//   gm  : D reads rows 0-63 cols 0-63; C writes exactly rows 0-63 cols 0-63.
__global__ __launch_bounds__(256) void fuse_k1(
    const float* __restrict__ x, const float* __restrict__ cw,
    const float* __restrict__ cb, float* __restrict__ acc, int use_ws)
{
    __shared__ short xsb [64 * XSB_S];    // 13312 B
    __shared__ short msk [64 * MSK_S];    // 13312 B
    __shared__ short mskT[96 * MSKT_S];   // 13824 B
    __shared__ short gm  [64 * G_S];      //  9216 B

    const int o = blockIdx.x;          // 0..23
    const int n = blockIdx.y;          // 0..31
    const int t = threadIdx.x;
    const int lane = t & 63;
    const int wv = t >> 6;             // 0..3
    const int lr = lane & 15;
    const int lq = lane >> 4;          // quad index 0..3

    const float* xg = x + (size_t)n * CC * HWSZ;
    float wk[KSZ];
    #pragma unroll
    for (int k = 0; k < KSZ; ++k) wk[k] = cw[o * KSZ + k];
    const float bias = cb[o];

    // ---- phase A: all writes disjoint ----
    const f32x4 z4 = {0.f, 0.f, 0.f, 0.f};
    // (a) stage x[n] data into xsb rows 0-48, cols 0-80
    for (int i = t; i < CC * HWSZ; i += 256) {
        int c = i / HWSZ, hw = i - c * HWSZ;
        xsb[c * XSB_S + hw] = f2b(xg[i]);
    }
    // (b) xsb pad cols 81..103 of rows 0-48 (scalar 81-87, b128 88-103)
    if (t < CC) {
        short* row = xsb + t * XSB_S;
        #pragma unroll
        for (int cq = 81; cq < 88; ++cq) row[cq] = 0;
        *(f32x4*)(row + 88) = z4;
        *(f32x4*)(row + 96) = z4;
    }
    // (c) xsb rows 49-63 full zero (15 rows x 13 b128-groups)
    for (int j = t; j < 15 * 13; j += 256) {
        int rr = j / 13, cg = j - rr * 13;
        *(f32x4*)(xsb + (49 + rr) * XSB_S + cg * 8) = z4;
    }
    // (d) msk zero, trimmed: rows 49-63 cols 0-95 (15x12 b128)
    for (int j = t; j < 15 * 12; j += 256) {
        int rr = j / 12, cg = j - rr * 12;
        *(f32x4*)(msk + (49 + rr) * MSK_S + cg * 8) = z4;
    }
    //     msk rows 0-48 cols 80-95 (2 b128/row; col 80 re-written in phase B
    //     after the barrier -> no race)
    for (int j = t; j < 49 * 2; j += 256) {
        int rr = j >> 1, half = j & 1;
        *(f32x4*)(msk + rr * MSK_S + 80 + half * 8) = z4;
    }
    // (e) mskT zero, trimmed: rows 0-80 cols 48-63 (2 b128/row, offset 96B
    //     aligned since 144*row%16==0; col 48 re-written in phase B)
    for (int j = t; j < 81 * 2; j += 256) {
        int rr = j >> 1, half = j & 1;
        *(f32x4*)(mskT + rr * MSKT_S + 48 + half * 8) = z4;
    }
    //     mskT rows 81-95 cols 0-63 (15x8 b128)
    for (int j = t; j < 15 * 8; j += 256) {
        int rr = j >> 3, cg = j & 7;
        *(f32x4*)(mskT + (81 + rr) * MSKT_S + cg * 8) = z4;
    }
    __syncthreads();

    // ---- phase B: conv + softmax (no max-sub); 4 rows per wave (row = lq).
    // Lane lr covers cols [4lr,4lr+4) (b64), col 64+lr, and col 80 on lr==0.
    #pragma unroll
    for (int it = 0; it < 4; ++it) {
        int dd = it * 16 + wv * 4 + lq;
        if (dd < CC) {
            float a0 = 0.f, a1 = 0.f, a2 = 0.f, a3 = 0.f, a4 = 0.f, a5 = 0.f;
            #pragma unroll
            for (int k = 0; k < KSZ; ++k) {
                int r = dd + k - PADSZ;
                if (r >= 0 && r < CC) {
                    const short* xr = xsb + r * XSB_S;
                    short4v xa = *(const short4v*)(xr + 4 * lr);
                    float w = wk[k];
                    a0 += w * b2f(xa[0]);
                    a1 += w * b2f(xa[1]);
                    a2 += w * b2f(xa[2]);
                    a3 += w * b2f(xa[3]);
                    a4 += w * b2f(xr[64 + lr]);
                    if (lr == 0) a5 += w * b2f(xr[80]);
                }
            }
            float e0 = __expf(a0 + bias), e1 = __expf(a1 + bias);
            float e2 = __expf(a2 + bias), e3 = __expf(a3 + bias);
            float e4 = __expf(a4 + bias);
            float e5 = (lr == 0) ? __expf(a5 + bias) : 0.f;
            float s = ((e0 + e1) + (e2 + e3)) + (e4 + e5);
            #pragma unroll
            for (int off = 8; off; off >>= 1) s += __shfl_xor(s, off, 64);
            float inv = __builtin_amdgcn_rcpf(s);
            short4v pk;
            pk[0] = f2b(e0 * inv); pk[1] = f2b(e1 * inv);
            pk[2] = f2b(e2 * inv); pk[3] = f2b(e3 * inv);
            short b4 = f2b(e4 * inv);
            short* mrow = msk + dd * MSK_S;
            *(short4v*)(mrow + 4 * lr) = pk;        // b64, 8B-aligned
            mrow[64 + lr] = b4;
            mskT[(4 * lr    ) * MSKT_S + dd] = pk[0];
            mskT[(4 * lr + 1) * MSKT_S + dd] = pk[1];
            mskT[(4 * lr + 2) * MSKT_S + dd] = pk[2];
            mskT[(4 * lr + 3) * MSKT_S + dd] = pk[3];
            mskT[(64 + lr   ) * MSKT_S + dd] = b4;
            if (lr == 0) {
                short b5 = f2b(e5 * inv);
                mrow[80] = b5;
                mskT[80 * MSKT_S + dd] = b5;
            }
        }
    }
    __syncthreads();

    // ---- phase C (MFMA): fkT[dd][c] = sum_hw msk[dd][hw] * xsb[c][hw]
    // M=dd (4 tiles, one per wave), N=c (4 tiles), K=hw (96, 3 steps).
    {
        short8 a2[3];
        #pragma unroll
        for (int ks = 0; ks < 3; ++ks)
            a2[ks] = *(const short8*)&msk[(wv * 16 + lr) * MSK_S + ks * 32 + lq * 8];
        #pragma unroll
        for (int nt = 0; nt < 4; ++nt) {
            f32x4 accv = {0.f, 0.f, 0.f, 0.f};
            #pragma unroll
            for (int ks = 0; ks < 3; ++ks) {
                short8 b = *(const short8*)&xsb[(nt * 16 + lr) * XSB_S + ks * 32 + lq * 8];
                accv = __builtin_amdgcn_mfma_f32_16x16x32_bf16(a2[ks], b, accv, 0, 0, 0);
            }
            // C-layout: lane holds fkT[dd = wv*16 + lq*4 + r][c = nt*16 + lr]
            short4v pk;
            #pragma unroll
            for (int r = 0; r < 4; ++r) {
                float v = accv[r];
                v = (v >= 0.f) ? v : 0.01f * v;
                pk[r] = f2b(v);
            }
            *(short4v*)&gm[(nt * 16 + lr) * G_S + wv * 16 + lq * 4] = pk;
        }
    }
    __syncthreads();

    // ---- phase D (MFMA): out_partial[c][hw] = sum_dd gm[c][dd] * mskT[hw][dd]
    // M=c (4 tiles, one per wave), N=hw (6 tiles), K=dd (64, 2 steps).
    {
        short* bws = (short*)acc + (size_t)(o * NN + n) * CC * HWSZ;  // bf16 ws
        float* dstn = acc + (size_t)n * CC * HWSZ;                    // fallback
        short8 a1[2];
        #pragma unroll
        for (int ks = 0; ks < 2; ++ks)
            a1[ks] = *(const short8*)&gm[(wv * 16 + lr) * G_S + ks * 32 + lq * 8];
        #pragma unroll
        for (int nt = 0; nt < 6; ++nt) {
            f32x4 accv = {0.f, 0.f, 0.f, 0.f};
            #pragma unroll
            for (int ks = 0; ks < 2; ++ks) {
                short8 b = *(const short8*)&mskT[(nt * 16 + lr) * MSKT_S + ks * 32 + lq * 8];
                accv = __builtin_amdgcn_mfma_f32_16x16x32_bf16(a1[ks], b, accv, 0, 0, 0);
            }
            int hw = nt * 16 + lr;
            if (hw < HWSZ) {
                int cb = wv * 16 + lq * 4;
                if (use_ws) {
                    #pragma unroll
                    for (int r = 0; r < 4; ++r) {
                        int c = cb + r;
                        if (c < CC) bws[c * HWSZ + hw] = f2b(accv[r]);
                    }
                } else {
                    #pragma unroll
                    for (int r = 0; r < 4; ++r) {
                        int c = cb + r;
                        if (c < CC) atomicAdd(dstn + c * HWSZ + hw, accv[r]);
                    }
                }
            }
        }
    }
}

// Per-element gather for k2: sum of 24 per-o bf16 partials + fp32 residual.
// 4 independent fp32 accumulators for memory-level parallelism.
__device__ __forceinline__ float k2_gather(
    const short* __restrict__ bws, const float* __restrict__ x, int c, int i)
{
    int n = i / HWSZ;
    int hw = i - n * HWSZ;
    int idx = (n * CC + c) * HWSZ + hw;
    const short* p = bws + idx;
    float v0 = x[idx], v1 = 0.f, v2 = 0.f, v3 = 0.f;
    #pragma unroll
    for (int o = 0; o < MSZ; o += 4) {
        v0 += b2f(p[(size_t)(o    ) * NCHW]);
        v1 += b2f(p[(size_t)(o + 1) * NCHW]);
        v2 += b2f(p[(size_t)(o + 2) * NCHW]);
        v3 += b2f(p[(size_t)(o + 3) * NCHW]);
    }
    return (v0 + v1) + (v2 + v3);
}

// Kernel 2 (ws path): one block per channel c (1024 thr). Sums the 24 per-o
// bf16 partials + fp32 residual, batch-norm over (N,H,W), writes d_out.
// De-scratched vs round 0: the per-thread element cache is 3 NAMED registers
// (v0,v1,v2) with a predicated third element (NHW = 2*1024 + 544), instead of
// a runtime-indexed vals[cnt++] array that allocates in scratch (rule #20).
__global__ __launch_bounds__(1024) void fuse_k2w(
    const short* __restrict__ bws, const float* __restrict__ x,
    const float* __restrict__ gamma, const float* __restrict__ beta,
    float* __restrict__ out)
{
    const int c = blockIdx.x;
    const int t = threadIdx.x;
    const bool has2 = (t + 2048) < NHW;
    float v0 = k2_gather(bws, x, c, t);
    float v1 = k2_gather(bws, x, c, t + 1024);
    float v2 = has2 ? k2_gather(bws, x, c, t + 2048) : 0.f;
    float sum = (v0 + v1) + v2;
    float sq  = (v0 * v0 + v1 * v1) + v2 * v2;
    #pragma unroll
    for (int off = 32; off; off >>= 1) {
        sum += __shfl_xor(sum, off, 64);
        sq  += __shfl_xor(sq, off, 64);
    }
    __shared__ float rs[16], rq[16];
    const int lane = t & 63, wv = t >> 6;
    if (lane == 0) { rs[wv] = sum; rq[wv] = sq; }
    __syncthreads();
    float ts = 0.f, tq = 0.f;
    #pragma unroll
    for (int w = 0; w < 16; ++w) { ts += rs[w]; tq += rq[w]; }
    const float invD = 1.f / (float)NHW;
    float mean = ts * invD;
    float var  = tq * invD - mean * mean;
    float scal = rsqrtf(var + 1e-5f) * gamma[c];
    float shft = beta[c] - mean * scal;
    {
        int i = t;
        int n = i / HWSZ, hw = i - n * HWSZ;
        out[(n * CC + c) * HWSZ + hw] = v0 * scal + shft;
    }
    {
        int i = t + 1024;
        int n = i / HWSZ, hw = i - n * HWSZ;
        out[(n * CC + c) * HWSZ + hw] = v1 * scal + shft;
    }
    if (has2) {
        int i = t + 2048;
        int n = i / HWSZ, hw = i - n * HWSZ;
        out[(n * CC + c) * HWSZ + hw] = v2 * scal + shft;
    }
}

// Kernel 2 (fallback, atomic path): residual add + batch-norm in-place on
// d_out. Same de-scratched 3-register structure.
__global__ __launch_bounds__(1024) void fuse_k2(
    float* __restrict__ out, const float* __restrict__ x,
    const float* __restrict__ gamma, const float* __restrict__ beta)
{
    const int c = blockIdx.x;
    const int t = threadIdx.x;
    const bool has2 = (t + 2048) < NHW;
    float v0, v1, v2 = 0.f;
    {
        int i = t;
        int n = i / HWSZ, hw = i - n * HWSZ;
        int idx = (n * CC + c) * HWSZ + hw;
        v0 = out[idx] + x[idx];
    }
    {
        int i = t + 1024;
        int n = i / HWSZ, hw = i - n * HWSZ;
        int idx = (n * CC + c) * HWSZ + hw;
        v1 = out[idx] + x[idx];
    }
    if (has2) {
        int i = t + 2048;
        int n = i / HWSZ, hw = i - n * HWSZ;
        int idx = (n * CC + c) * HWSZ + hw;
        v2 = out[idx] + x[idx];
    }
    float sum = (v0 + v1) + v2;
    float sq  = (v0 * v0 + v1 * v1) + v2 * v2;
    #pragma unroll
    for (int off = 32; off; off >>= 1) {
        sum += __shfl_xor(sum, off, 64);
        sq  += __shfl_xor(sq, off, 64);
    }
    __shared__ float rs[16], rq[16];
    const int lane = t & 63, wv = t >> 6;
    if (lane == 0) { rs[wv] = sum; rq[wv] = sq; }
    __syncthreads();
    float ts = 0.f, tq = 0.f;
    #pragma unroll
    for (int w = 0; w < 16; ++w) { ts += rs[w]; tq += rq[w]; }
    const float invD = 1.f / (float)NHW;
    float mean = ts * invD;
    float var  = tq * invD - mean * mean;
    float scal = rsqrtf(var + 1e-5f) * gamma[c];
    float shft = beta[c] - mean * scal;
    {
        int i = t;
        int n = i / HWSZ, hw = i - n * HWSZ;
        out[(n * CC + c) * HWSZ + hw] = v0 * scal + shft;
    }
    {
        int i = t + 1024;
        int n = i / HWSZ, hw = i - n * HWSZ;
        out[(n * CC + c) * HWSZ + hw] = v1 * scal + shft;
    }
    if (has2) {
        int i = t + 2048;
        int n = i / HWSZ, hw = i - n * HWSZ;
        out[(n * CC + c) * HWSZ + hw] = v2 * scal + shft;
    }
}

extern "C" void kernel_launch(void* const* d_in, const int* in_sizes, int n_in,
                              void* d_out, int out_size, void* d_ws, size_t ws_size,
                              hipStream_t stream) {
    const float* x     = (const float*)d_in[0];
    const float* cw    = (const float*)d_in[1];
    const float* cb    = (const float*)d_in[2];
    const float* gamma = (const float*)d_in[3];
    const float* beta  = (const float*)d_in[4];
    float* out = (float*)d_out;

    const size_t need = (size_t)MSZ * NCHW * sizeof(short);   // 6.1 MB (bf16)
    if (ws_size >= need) {
        // Best-known 2-node structure (round 0, 79.96us verified).
        fuse_k1<<<dim3(MSZ, NN), 256, 0, stream>>>(x, cw, cb, (float*)d_ws, 1);
        fuse_k2w<<<CC, 1024, 0, stream>>>((const short*)d_ws, x, gamma, beta, out);
    } else {
        hipMemsetAsync(out, 0, (size_t)NCHW * sizeof(float), stream);
        fuse_k1<<<dim3(MSZ, NN), 256, 0, stream>>>(x, cw, cb, out, 0);
        fuse_k2<<<CC, 1024, 0, stream>>>(out, x, gamma, beta);
    }
}